// Round 4
// baseline (228.858 us; speedup 1.0000x reference)
//
#include <hip/hip_runtime.h>

#define NODES_H 128
#define NB_K 16

typedef __attribute__((ext_vector_type(8))) short bf16x8;
typedef __attribute__((ext_vector_type(4))) float f32x4;

// fp32 -> bf16 with round-to-nearest-even (bit trick, no NaN inputs here)
__device__ __forceinline__ short f2bf(float f) {
    unsigned u = __float_as_uint(f);
    unsigned r = (u + 0x7fffu + ((u >> 16) & 1u)) >> 16;
    return (short)r;
}

__device__ __forceinline__ bf16x8 pack8(float4 x, float4 y) {
    bf16x8 v;
    v[0] = f2bf(x.x); v[1] = f2bf(x.y); v[2] = f2bf(x.z); v[3] = f2bf(x.w);
    v[4] = f2bf(y.x); v[5] = f2bf(y.y); v[6] = f2bf(y.z); v[7] = f2bf(y.w);
    return v;
}

// ---------------------------------------------------------------------------
// Kernel 1: per-node attention score via bf16 MFMA
//   score[n] = sum_j lrelu( (e[n,:] . Wa[j,:]) + b[j] ) * ua[j]
// One wave = 16 nodes (one 16x16x32 MFMA M-tile), j covered by 8 col-tiles,
// K=128 by 4 chunks -> 32 MFMAs/group. Wa packed once per block into LDS as
// per-lane B fragments (ds_read_b128, lane-consecutive -> conflict-free).
// A and B packed with the SAME (lane,elem)->k rule (k = kk*32 + (lane>>4)*8
// + elem), so any HW K-ordering is self-consistent. D layout (HW-verified):
// col j = lane&15, node row = (lane>>4)*4 + reg. Bias enters as the
// accumulator init (bias is a column vector in D).
// ---------------------------------------------------------------------------
__global__ __launch_bounds__(256) void score_kernel(
    const float* __restrict__ e, const float* __restrict__ Wa,
    const float* __restrict__ bias, const float* __restrict__ ua,
    float* __restrict__ scores, int nNodes)
{
    __shared__ bf16x8 Bfrag[8][4][64];   // 32 KB

    const int t = threadIdx.x;
    // one-time pack: slot s = (jt, kk, l); 8 slots per thread
    #pragma unroll
    for (int q = 0; q < 8; ++q) {
        int s = t * 8 + q;
        int jt = s >> 8, kk = (s >> 6) & 3, l = s & 63;
        const float* wrow = Wa + (size_t)(jt * 16 + (l & 15)) * NODES_H
                               + kk * 32 + ((l >> 4) * 8);
        float4 x = *(const float4*)wrow;
        float4 y = *(const float4*)(wrow + 4);
        Bfrag[jt][kk][l] = pack8(x, y);
    }
    __syncthreads();

    const int lane = t & 63;
    const int wave = blockIdx.x * (blockDim.x >> 6) + (t >> 6);
    const int nGroups = (nNodes + 15) >> 4;   // 6250 (exact: 100000 = 16*6250)
    if (wave >= nGroups) return;
    const int n0 = wave << 4;

    // per-lane bias / ua for col j = jt*16 + (lane&15)
    float b_f[8], u_f[8];
    #pragma unroll
    for (int jt = 0; jt < 8; ++jt) {
        b_f[jt] = bias[jt * 16 + (lane & 15)];
        u_f[jt] = ua[jt * 16 + (lane & 15)];
    }

    // A fragments: node row n0+(lane&15), k = kk*32 + (lane>>4)*8 + [0..7]
    int arow = n0 + (lane & 15);
    if (arow >= nNodes) arow = nNodes - 1;          // safety clamp (no-op here)
    const float* ap = e + (size_t)arow * NODES_H + ((lane >> 4) * 8);
    bf16x8 a[4];
    #pragma unroll
    for (int kk = 0; kk < 4; ++kk) {
        float4 x = *(const float4*)(ap + kk * 32);
        float4 y = *(const float4*)(ap + kk * 32 + 4);
        a[kk] = pack8(x, y);
    }

    float sr[4] = {0.f, 0.f, 0.f, 0.f};
    #pragma unroll
    for (int jt = 0; jt < 8; ++jt) {
        f32x4 c = {b_f[jt], b_f[jt], b_f[jt], b_f[jt]};
        #pragma unroll
        for (int kk = 0; kk < 4; ++kk)
            c = __builtin_amdgcn_mfma_f32_16x16x32_bf16(a[kk], Bfrag[jt][kk][lane], c, 0, 0, 0);
        #pragma unroll
        for (int r = 0; r < 4; ++r) {
            float h = c[r];
            h = (h > 0.f) ? h : 0.1f * h;          // leaky_relu(0.1)
            sr[r] = fmaf(h, u_f[jt], sr[r]);
        }
    }

    // sum over the 16 j-cols: butterfly across each 16-lane group
    #pragma unroll
    for (int off = 1; off < 16; off <<= 1) {
        #pragma unroll
        for (int r = 0; r < 4; ++r)
            sr[r] += __shfl_xor(sr[r], off, 64);
    }

    // lanes 0,16,32,48 hold nodes n0 + (lane>>4)*4 + [0..3] -> float4 store
    if ((lane & 15) == 0) {
        int nidx = n0 + ((lane >> 4) << 2);
        if (nidx + 3 < nNodes)
            *(float4*)(scores + nidx) = make_float4(sr[0], sr[1], sr[2], sr[3]);
        else
            for (int r = 0; r < 4 && nidx + r < nNodes; ++r)
                scores[nidx + r] = sr[r];
    }
}

// ---------------------------------------------------------------------------
// Kernel 2: softmax over K neighbor scores + weighted aggregation
//   out[n,:] = e[n,:] + sum_k softmax_k(scores[nb[n,k]]) * e[nb[n,k],:]
// One wave per node; lane l owns elements {2l, 2l+1} via float2 -> one
// wave-load = one full 512B row. Indices and scores go through the scalar
// path (wave-uniform addresses). All 17 row-loads issued before the FMA
// chain for memory-level parallelism.
// ---------------------------------------------------------------------------
__global__ __launch_bounds__(256) void agg_kernel(
    const float* __restrict__ e, const int* __restrict__ nbrs,
    const float* __restrict__ scores, float* __restrict__ out, int nNodes)
{
    const int lane = threadIdx.x & 63;
    const int wave = (int)((blockIdx.x * blockDim.x + threadIdx.x) >> 6);
    if (wave >= nNodes) return;
    const int nu = __builtin_amdgcn_readfirstlane(wave);

    // neighbor indices: uniform address -> scalar loads
    int idx[NB_K];
    #pragma unroll
    for (int k = 0; k < NB_K; ++k)
        idx[k] = __builtin_amdgcn_readfirstlane(nbrs[nu * NB_K + k]);

    // neighbor scores: uniform scattered scalar loads (400KB array, cache-hot)
    float s[NB_K];
    #pragma unroll
    for (int k = 0; k < NB_K; ++k) s[k] = scores[idx[k]];

    // softmax over the 16 values (redundant per lane)
    float mx = s[0];
    #pragma unroll
    for (int k = 1; k < NB_K; ++k) mx = fmaxf(mx, s[k]);
    float sum = 0.f;
    #pragma unroll
    for (int k = 0; k < NB_K; ++k) { s[k] = __expf(s[k] - mx); sum += s[k]; }
    const float inv = 1.0f / sum;

    // self row + all neighbor-row gathers in flight before accumulation
    const float2* e2 = (const float2*)e;
    const size_t base2 = (size_t)nu * (NODES_H / 2) + lane;
    float2 self = e2[base2];

    float2 g[NB_K];
    #pragma unroll
    for (int k = 0; k < NB_K; ++k)
        g[k] = e2[(size_t)idx[k] * (NODES_H / 2) + lane];

    float o0 = self.x, o1 = self.y;
    #pragma unroll
    for (int k = 0; k < NB_K; ++k) {
        const float w = s[k] * inv;
        o0 = fmaf(w, g[k].x, o0);
        o1 = fmaf(w, g[k].y, o1);
    }

    float2* out2 = (float2*)out;
    out2[base2] = make_float2(o0, o1);
}

// ---------------------------------------------------------------------------
extern "C" void kernel_launch(void* const* d_in, const int* in_sizes, int n_in,
                              void* d_out, int out_size, void* d_ws, size_t ws_size,
                              hipStream_t stream) {
    const float* e   = (const float*)d_in[0];
    const float* Wa  = (const float*)d_in[1];
    const float* Wb  = (const float*)d_in[2];
    const float* ua  = (const float*)d_in[3];
    const int*   nb  = (const int*)d_in[4];
    float* out = (float*)d_out;
    float* scores = (float*)d_ws;   // N floats = 400 KB scratch

    const int nNodes = in_sizes[0] / NODES_H;   // 100000

    // Kernel 1: one wave per 16-node group; 6250 groups -> 1563 blocks x 4 waves.
    const int nGroups = (nNodes + 15) / 16;
    const int blocks1 = (nGroups + 3) / 4;
    score_kernel<<<blocks1, 256, 0, stream>>>(e, Wa, Wb, ua, scores, nNodes);

    // Kernel 2: one wave per node, direct mapping (exactly 100000 waves).
    int blocks2 = (nNodes + 3) / 4;   // 4 waves per 256-thread block
    agg_kernel<<<blocks2, 256, 0, stream>>>(e, nb, scores, out, nNodes);
}